// Round 5
// 193.987 us; speedup vs baseline: 1.2010x; 1.2010x over previous
//
#include <hip/hip_runtime.h>
#include <stdint.h>

#define AS1 __attribute__((address_space(1)))
#define AS3 __attribute__((address_space(3)))

typedef __attribute__((ext_vector_type(8))) short bf16x8;
typedef __attribute__((ext_vector_type(4))) float f32x4;

// ================= Cl(4,1) ~= M4(C) isomorphism, built at compile time =================
// Generators (monomial 4x4 complex, entries i^ph):
//  E0=s1(x)I, E1=s2(x)I, E2=s3(x)s1, E3=s3(x)s2 (square +1); E4=i*s3(x)s3 (square -1).
// Blade A (5-bit mask) -> M_A = product of E_b over set bits, ascending. Each M_A is
// monomial: M_A[r, col[r]] = i^ph[r].

struct Mono { int col[4]; int ph[4]; };

constexpr Mono mono_mul(Mono A, Mono B) {
    Mono R{};
    for (int r = 0; r < 4; ++r) {
        int k = A.col[r];
        R.col[r] = B.col[k];
        R.ph[r] = (A.ph[r] + B.ph[k]) & 3;
    }
    return R;
}

constexpr Mono gen(int g) {
    Mono E{};
    for (int r = 0; r < 4; ++r) {
        int r1 = (r >> 1) & 1, r0 = r & 1;
        if (g == 0)      { E.col[r] = r ^ 2; E.ph[r] = 0; }
        else if (g == 1) { E.col[r] = r ^ 2; E.ph[r] = r1 ? 1 : 3; }
        else if (g == 2) { E.col[r] = r ^ 1; E.ph[r] = r1 ? 2 : 0; }
        else if (g == 3) { E.col[r] = r ^ 1; E.ph[r] = ((r1 ? 2 : 0) + (r0 ? 1 : 3)) & 3; }
        else             { E.col[r] = r;     E.ph[r] = (1 + (r1 ? 2 : 0) + (r0 ? 2 : 0)) & 3; }
    }
    return E;
}

struct Blades { Mono m[32]; };
constexpr Blades make_blades() {
    Blades B{};
    for (int A = 0; A < 32; ++A) {
        Mono M{};
        for (int r = 0; r < 4; ++r) { M.col[r] = r; M.ph[r] = 0; }
        for (int g = 0; g < 5; ++g)
            if ((A >> g) & 1) M = mono_mul(M, gen(g));
        B.m[A] = M;
    }
    return B;
}
constexpr Blades BL = make_blades();

// Forward table: matrix entry (row r, col c, rc=0:Re/1:Im) = sum of 4 signed blade coeffs.
struct FwdTab { int bl[4][4][2][4]; float sg[4][4][2][4]; };
constexpr FwdTab make_fwd() {
    FwdTab T{};
    int cnt[4][4][2] = {};
    for (int A = 0; A < 32; ++A)
        for (int r = 0; r < 4; ++r) {
            int c = BL.m[A].col[r], p = BL.m[A].ph[r];
            int rc = p & 1;
            int& n = cnt[r][c][rc];
            T.bl[r][c][rc][n] = A;
            T.sg[r][c][rc][n] = (p & 2) ? -1.f : 1.f;
            ++n;
        }
    return T;
}
constexpr FwdTab FT = make_fwd();

__device__ inline unsigned short f2bf(float f) {
    uint32_t u = __float_as_uint(f);
    u += 0x7FFFu + ((u >> 16) & 1u);
    return (unsigned short)(u >> 16);
}

// ---- kernel 1 (fused transforms) ----
// blocks [0,2048):    x[n,i,0..31] -> X̂ rows: Xb[(n*4+b)][i*8 + c*2 + rc]  (bf16)
// blocks [2048,2304): w[o,i,0..31] -> Ŵ real-embed: Wr[(o*8+ra*4+a)][i*8 + c*2 + rc]
__global__ __launch_bounds__(256) void xform_kernel(const float* __restrict__ x,
                                                    const float* __restrict__ w,
                                                    unsigned short* __restrict__ Xb,
                                                    unsigned short* __restrict__ Wr) {
    if (blockIdx.x < 2048) {
        int t = blockIdx.x * 256 + threadIdx.x;     // t = n*256 + i
        int i = t & 255, n = t >> 8;
        float v[32];
        const float4* xp = (const float4*)(x + (size_t)t * 32);
#pragma unroll
        for (int q = 0; q < 8; ++q) {
            float4 f = xp[q];
            v[q * 4 + 0] = f.x; v[q * 4 + 1] = f.y; v[q * 4 + 2] = f.z; v[q * 4 + 3] = f.w;
        }
#pragma unroll
        for (int b = 0; b < 4; ++b) {
            union { unsigned short s[8]; uint4 u; } r;
#pragma unroll
            for (int c = 0; c < 4; ++c)
#pragma unroll
                for (int rc = 0; rc < 2; ++rc) {
                    float s = 0.f;
#pragma unroll
                    for (int j = 0; j < 4; ++j)
                        s += FT.sg[c][b][rc][j] * v[FT.bl[c][b][rc][j]];
                    r.s[c * 2 + rc] = f2bf(s);
                }
            *((uint4*)(Xb + (size_t)(n * 4 + b) * 2048 + i * 8)) = r.u;
        }
    } else {
        int t = (blockIdx.x - 2048) * 256 + threadIdx.x;   // t = o*256 + i
        int i = t & 255, o = t >> 8;
        float v[32];
        const float4* wp = (const float4*)(w + (size_t)t * 32);
#pragma unroll
        for (int q = 0; q < 8; ++q) {
            float4 f = wp[q];
            v[q * 4 + 0] = f.x; v[q * 4 + 1] = f.y; v[q * 4 + 2] = f.z; v[q * 4 + 3] = f.w;
        }
        float Re[4][4], Im[4][4];
#pragma unroll
        for (int a = 0; a < 4; ++a)
#pragma unroll
            for (int c = 0; c < 4; ++c) {
                float sr = 0.f, si = 0.f;
#pragma unroll
                for (int j = 0; j < 4; ++j) {
                    sr += FT.sg[a][c][0][j] * v[FT.bl[a][c][0][j]];
                    si += FT.sg[a][c][1][j] * v[FT.bl[a][c][1][j]];
                }
                Re[a][c] = sr; Im[a][c] = si;
            }
#pragma unroll
        for (int ra = 0; ra < 2; ++ra)
#pragma unroll
            for (int a = 0; a < 4; ++a) {
                int m = o * 8 + ra * 4 + a;   // complete multivectors per 8-row group
                union { unsigned short s[8]; uint4 u; } r;
#pragma unroll
                for (int c = 0; c < 4; ++c) {
                    float v0 = ra == 0 ? Re[a][c] : Im[a][c];
                    float v1 = ra == 0 ? -Im[a][c] : Re[a][c];
                    r.s[c * 2 + 0] = f2bf(v0);
                    r.s[c * 2 + 1] = f2bf(v1);
                }
                *((uint4*)(Wr + (size_t)m * 2048 + i * 8)) = r.u;
            }
    }
}

// ---- kernel 2: deep-pipelined 256x256 GEMM + fused inverse transform + L2 normalize ----
// C_virtual[2048,8192] = Wr * Xb^T.  Structure (guide T3+T4+T2+T5):
//   * BK=32, 4-buffer LDS ring (128 KiB), 3-deep global_load_lds prefetch,
//     counted s_waitcnt vmcnt(8) — never drained to 0 in the main loop,
//     ONE s_barrier per K-step.
//   * T2 swizzle: 16B-chunk index ^= (row>>1)&3 applied to BOTH the pre-swizzled
//     global source (global_load_lds writes linearly) and the ds_read address.
//   * T5 setprio(1) around the 32-MFMA cluster.
// Each wave owns a 128x64 C patch -> every output multivector is wave-local, so the
// epilogue needs no cross-wave barriers: 4 stripes of 32x64 f32 per-wave scratch.
// NOTE: all acc[][] indexing is compile-time (full unroll) — runtime indexing demotes
// the accumulator to scratch (prior session R4: 5x regression).
__global__ __launch_bounds__(512, 2) void gemm_kernel(const unsigned short* __restrict__ A,
                                                      const unsigned short* __restrict__ B,
                                                      float* __restrict__ out) {
    const int K = 2048;
    const int NT = 64;                         // K / 32
    __shared__ alignas(16) unsigned short SM[4 * 16384];   // 128 KB: 4 x (A 8192 + B 8192)

    const int tid = threadIdx.x;
    const int wid = tid >> 6, lane = tid & 63;
    const int lm = lane & 15, quad = lane >> 4;
    const int wm = wid >> 2, wn = wid & 3;     // 2 x 4 wave grid
    const int row0 = blockIdx.y * 256;         // A rows (M = o*8+ra*4+a)
    const int col0 = blockIdx.x * 256;         // B rows (N = n*4+c)

    // staging source offsets: chunk g = p*512+tid; r=g>>2; c=g&3; src chunk = c^((r>>1)&3)
    size_t gA[2], gB[2];
    int ldsA[2], ldsB[2];
#pragma unroll
    for (int p = 0; p < 2; ++p) {
        int g = p * 512 + tid;
        int r = g >> 2, c = g & 3;
        int sc = c ^ ((r >> 1) & 3);
        gA[p] = (size_t)(row0 + r) * K + sc * 8;
        gB[p] = (size_t)(col0 + r) * K + sc * 8;
        ldsA[p] = (p * 512 + wid * 64) * 8;           // wave-uniform LDS base (shorts)
        ldsB[p] = 8192 + (p * 512 + wid * 64) * 8;
    }

    // fragment read offsets (swizzled to match): byte = row*64 + ((quad^((row>>1)&3))*16)
    const int swz = (lm >> 1) & 3;
    const int aoff = (wm * 128 + lm) * 32 + (quad ^ swz) * 8;
    const int boff = 8192 + (wn * 64 + lm) * 32 + (quad ^ swz) * 8;

    f32x4 acc[8][4];
#pragma unroll
    for (int i = 0; i < 8; ++i)
#pragma unroll
        for (int j = 0; j < 4; ++j) acc[i][j] = (f32x4){0.f, 0.f, 0.f, 0.f};

    auto ISSUE = [&](int t) {
        const int bb = (t & 3) * 16384;
        const int k0 = t * 32;
#pragma unroll
        for (int p = 0; p < 2; ++p) {
            __builtin_amdgcn_global_load_lds((const AS1 void*)(A + gA[p] + k0),
                                             (AS3 void*)(&SM[bb + ldsA[p]]), 16, 0, 0);
            __builtin_amdgcn_global_load_lds((const AS1 void*)(B + gB[p] + k0),
                                             (AS3 void*)(&SM[bb + ldsB[p]]), 16, 0, 0);
        }
    };
    auto COMPUTE = [&](int t) {
        const int bb = (t & 3) * 16384;
        bf16x8 av[8], bv[4];
#pragma unroll
        for (int fn = 0; fn < 4; ++fn) bv[fn] = *(const bf16x8*)&SM[bb + boff + fn * 512];
#pragma unroll
        for (int fm = 0; fm < 8; ++fm) av[fm] = *(const bf16x8*)&SM[bb + aoff + fm * 512];
        __builtin_amdgcn_s_setprio(1);
#pragma unroll
        for (int fm = 0; fm < 8; ++fm)
#pragma unroll
            for (int fn = 0; fn < 4; ++fn)
                acc[fm][fn] = __builtin_amdgcn_mfma_f32_16x16x32_bf16(av[fm], bv[fn],
                                                                      acc[fm][fn], 0, 0, 0);
        __builtin_amdgcn_s_setprio(0);
    };

    // prologue: 3 K-tiles in flight
    ISSUE(0); ISSUE(1); ISSUE(2);
    for (int t = 0; t < NT - 3; ++t) {
        asm volatile("s_waitcnt vmcnt(8)" ::: "memory");   // tile t resident; t+1,t+2 in flight
        __builtin_amdgcn_s_barrier();
        ISSUE(t + 3);                                       // overwrites buf (t-1)&3: safe, all
        COMPUTE(t);                                         // readers consumed it before barrier
    }
    asm volatile("s_waitcnt vmcnt(8)" ::: "memory");
    __builtin_amdgcn_s_barrier();
    COMPUTE(NT - 3);
    asm volatile("s_waitcnt vmcnt(4)" ::: "memory");
    __builtin_amdgcn_s_barrier();
    COMPUTE(NT - 2);
    asm volatile("s_waitcnt vmcnt(0)" ::: "memory");
    __builtin_amdgcn_s_barrier();
    COMPUTE(NT - 1);
    __syncthreads();   // LDS reuse boundary: K-loop buffers -> per-wave epilogue scratch

    // ---- fused epilogue: per-wave 32x64 f32 stripes, no cross-wave sync needed ----
    float* scrw = (float*)SM + wid * 2048;     // 8 KB per wave (64 KB total)
    const int nl = lane >> 2, ol = lane & 3;   // 4 consecutive o's in adjacent lanes
#pragma unroll
    for (int s = 0; s < 4; ++s) {              // fm pair {2s, 2s+1} = C rows [s*32, s*32+32)
#pragma unroll
        for (int h = 0; h < 2; ++h)
#pragma unroll
            for (int fn = 0; fn < 4; ++fn)
#pragma unroll
                for (int r = 0; r < 4; ++r) {
                    int rw = h * 16 + quad * 4 + r;
                    int cc = (fn * 16 + lm) ^ (quad << 3);   // (rw>>2)&3 == quad
                    scrw[rw * 64 + cc] = acc[s * 2 + h][fn][r];
                }
        asm volatile("s_waitcnt lgkmcnt(0)" ::: "memory");
        float V[32];   // V[ra*16 + a*4 + c]
#pragma unroll
        for (int u = 0; u < 8; ++u) {          // u = ra*4 + a
            int row = ol * 8 + u;
            int cb = (nl * 4) ^ (((row >> 2) & 3) << 3);
            float4 f = *(const float4*)&scrw[row * 64 + cb];
            int vi = (u >> 2) * 16 + (u & 3) * 4;
            V[vi + 0] = f.x; V[vi + 1] = f.y; V[vi + 2] = f.z; V[vi + 3] = f.w;
        }
        float xa[32];
        float ss = 0.f;
#pragma unroll
        for (int Ab = 0; Ab < 32; ++Ab) {
            float sv = 0.f;
#pragma unroll
            for (int a = 0; a < 4; ++a) {
                const int c = BL.m[Ab].col[a];
                const int p = BL.m[Ab].ph[a];
                float vv = V[(p & 1) * 16 + a * 4 + c];
                sv += (p & 2) ? -vv : vv;
            }
            sv *= 0.25f;
            xa[Ab] = sv;
            ss += sv * sv;
        }
        float inv = rsqrtf(ss + 1e-6f);
        int o = (row0 >> 3) + wm * 16 + s * 4 + ol;
        int n = (col0 >> 2) + wn * 16 + nl;
        float4* op = (float4*)(out + ((size_t)n * 256 + o) * 32);
#pragma unroll
        for (int q = 0; q < 8; ++q) {
            float4 f;
            f.x = xa[q * 4 + 0] * inv; f.y = xa[q * 4 + 1] * inv;
            f.z = xa[q * 4 + 2] * inv; f.w = xa[q * 4 + 3] * inv;
            op[q] = f;
        }
        asm volatile("s_waitcnt lgkmcnt(0)" ::: "memory");   // stripe reads done before rewrite
    }
}

extern "C" void kernel_launch(void* const* d_in, const int* in_sizes, int n_in,
                              void* d_out, int out_size, void* d_ws, size_t ws_size,
                              hipStream_t stream) {
    const float* x = (const float*)d_in[0];   // [4,512,256,32]
    const float* w = (const float*)d_in[1];   // [256,256,32]
    float* out = (float*)d_out;               // [4,512,256,32]

    unsigned short* Wr = (unsigned short*)d_ws;                             //  8,388,608 B
    unsigned short* Xb = (unsigned short*)((char*)d_ws + 8388608);          // 33,554,432 B

    hipLaunchKernelGGL(xform_kernel, dim3(2304),  dim3(256), 0, stream, x, w, Xb, Wr);
    hipLaunchKernelGGL(gemm_kernel,  dim3(32, 8), dim3(512), 0, stream, Wr, Xb, out);
}

// Round 9
// 190.665 us; speedup vs baseline: 1.2219x; 1.0174x over previous
//
#include <hip/hip_runtime.h>
#include <stdint.h>

#define AS1 __attribute__((address_space(1)))
#define AS3 __attribute__((address_space(3)))

typedef __attribute__((ext_vector_type(8))) short bf16x8;
typedef __attribute__((ext_vector_type(4))) float f32x4;

// ================= Cl(4,1) ~= M4(C) isomorphism, built at compile time =================
struct Mono { int col[4]; int ph[4]; };

constexpr Mono mono_mul(Mono A, Mono B) {
    Mono R{};
    for (int r = 0; r < 4; ++r) {
        int k = A.col[r];
        R.col[r] = B.col[k];
        R.ph[r] = (A.ph[r] + B.ph[k]) & 3;
    }
    return R;
}

constexpr Mono gen(int g) {
    Mono E{};
    for (int r = 0; r < 4; ++r) {
        int r1 = (r >> 1) & 1, r0 = r & 1;
        if (g == 0)      { E.col[r] = r ^ 2; E.ph[r] = 0; }
        else if (g == 1) { E.col[r] = r ^ 2; E.ph[r] = r1 ? 1 : 3; }
        else if (g == 2) { E.col[r] = r ^ 1; E.ph[r] = r1 ? 2 : 0; }
        else if (g == 3) { E.col[r] = r ^ 1; E.ph[r] = ((r1 ? 2 : 0) + (r0 ? 1 : 3)) & 3; }
        else             { E.col[r] = r;     E.ph[r] = (1 + (r1 ? 2 : 0) + (r0 ? 2 : 0)) & 3; }
    }
    return E;
}

struct Blades { Mono m[32]; };
constexpr Blades make_blades() {
    Blades B{};
    for (int A = 0; A < 32; ++A) {
        Mono M{};
        for (int r = 0; r < 4; ++r) { M.col[r] = r; M.ph[r] = 0; }
        for (int g = 0; g < 5; ++g)
            if ((A >> g) & 1) M = mono_mul(M, gen(g));
        B.m[A] = M;
    }
    return B;
}
constexpr Blades BL = make_blades();

struct FwdTab { int bl[4][4][2][4]; float sg[4][4][2][4]; };
constexpr FwdTab make_fwd() {
    FwdTab T{};
    int cnt[4][4][2] = {};
    for (int A = 0; A < 32; ++A)
        for (int r = 0; r < 4; ++r) {
            int c = BL.m[A].col[r], p = BL.m[A].ph[r];
            int rc = p & 1;
            int& n = cnt[r][c][rc];
            T.bl[r][c][rc][n] = A;
            T.sg[r][c][rc][n] = (p & 2) ? -1.f : 1.f;
            ++n;
        }
    return T;
}
constexpr FwdTab FT = make_fwd();

__device__ inline unsigned short f2bf(float f) {
    uint32_t u = __float_as_uint(f);
    u += 0x7FFFu + ((u >> 16) & 1u);
    return (unsigned short)(u >> 16);
}

// ---- kernel 1 (fused transforms) ----
// x-branch stages the block's 256 multivectors through LDS so global reads are
// fully coalesced (1 KB/wave-instr) instead of 16B-per-lane at 128B stride (AoS).
// LDS unit (16B) swizzle L = (U&~7)|((U&7)^((U>>3)&7)) makes the per-mv readback
// 2-way bank aliased (free) per quarter-wave.
__global__ __launch_bounds__(256) void xform_kernel(const float* __restrict__ x,
                                                    const float* __restrict__ w,
                                                    unsigned short* __restrict__ Xb,
                                                    unsigned short* __restrict__ Wr) {
    __shared__ alignas(16) float XS[8192];   // 32 KB: 256 mv x 32 f32
    if (blockIdx.x < 2048) {
        int tid = threadIdx.x;
        const float4* xp = (const float4*)(x + (size_t)blockIdx.x * 8192);
        float4 ld[8];
#pragma unroll
        for (int r = 0; r < 8; ++r) ld[r] = xp[r * 256 + tid];   // coalesced
#pragma unroll
        for (int r = 0; r < 8; ++r) {
            int U = r * 256 + tid;
            int L = (U & ~7) | ((U & 7) ^ ((U >> 3) & 7));
            *(float4*)&XS[L * 4] = ld[r];
        }
        __syncthreads();
        float v[32];
#pragma unroll
        for (int q = 0; q < 8; ++q) {
            int L = tid * 8 + (q ^ (tid & 7));
            float4 f = *(const float4*)&XS[L * 4];
            v[q * 4 + 0] = f.x; v[q * 4 + 1] = f.y; v[q * 4 + 2] = f.z; v[q * 4 + 3] = f.w;
        }
        int t = blockIdx.x * 256 + tid;          // t = n*256 + i
        int i = t & 255, n = t >> 8;
#pragma unroll
        for (int b = 0; b < 4; ++b) {
            union { unsigned short s[8]; uint4 u; } r;
#pragma unroll
            for (int c = 0; c < 4; ++c)
#pragma unroll
                for (int rc = 0; rc < 2; ++rc) {
                    float s = 0.f;
#pragma unroll
                    for (int j = 0; j < 4; ++j)
                        s += FT.sg[c][b][rc][j] * v[FT.bl[c][b][rc][j]];
                    r.s[c * 2 + rc] = f2bf(s);
                }
            *((uint4*)(Xb + (size_t)(n * 4 + b) * 2048 + i * 8)) = r.u;
        }
    } else {
        int t = (blockIdx.x - 2048) * 256 + threadIdx.x;   // t = o*256 + i
        int i = t & 255, o = t >> 8;
        float v[32];
        const float4* wp = (const float4*)(w + (size_t)t * 32);
#pragma unroll
        for (int q = 0; q < 8; ++q) {
            float4 f = wp[q];
            v[q * 4 + 0] = f.x; v[q * 4 + 1] = f.y; v[q * 4 + 2] = f.z; v[q * 4 + 3] = f.w;
        }
        float Re[4][4], Im[4][4];
#pragma unroll
        for (int a = 0; a < 4; ++a)
#pragma unroll
            for (int c = 0; c < 4; ++c) {
                float sr = 0.f, si = 0.f;
#pragma unroll
                for (int j = 0; j < 4; ++j) {
                    sr += FT.sg[a][c][0][j] * v[FT.bl[a][c][0][j]];
                    si += FT.sg[a][c][1][j] * v[FT.bl[a][c][1][j]];
                }
                Re[a][c] = sr; Im[a][c] = si;
            }
#pragma unroll
        for (int ra = 0; ra < 2; ++ra)
#pragma unroll
            for (int a = 0; a < 4; ++a) {
                int m = o * 8 + ra * 4 + a;
                union { unsigned short s[8]; uint4 u; } r;
#pragma unroll
                for (int c = 0; c < 4; ++c) {
                    float v0 = ra == 0 ? Re[a][c] : Im[a][c];
                    float v1 = ra == 0 ? -Im[a][c] : Re[a][c];
                    r.s[c * 2 + 0] = f2bf(v0);
                    r.s[c * 2 + 1] = f2bf(v1);
                }
                *((uint4*)(Wr + (size_t)m * 2048 + i * 8)) = r.u;
            }
    }
}

// ---- kernel 2: phase-interleaved 256x256 GEMM (BK=64) + fused epilogue ----
// C_virtual[2048,8192] = Wr * Xb^T.
// LDS: 2-buffer ring x 4 planes/tile {A.ks0, B.ks0, A.ks1, B.ks1}, 16 KB each (128 KB).
// Plane layout [256 rows][32 shorts], 64 B row stride; 16B-chunk swizzle j^=(row>>1)&3
// applied to BOTH the pre-swizzled global source and the ds_read address (rule 21).
// Per tile: 4 phases; each phase = {ds_read frag subtile | stage ONE plane of tile t+1
// | barrier | setprio(1) 16 MFMA setprio(0)}. Counted s_waitcnt vmcnt(4) + barrier at
// phases 0 and 2 only (never 0 until the final tile).
// Race audit: stages during tile t target buf[(t+1)&1] != read buffer; plane staging
// order (slot s staged at phase s) + per-wave FIFO vmcnt(4) guarantees phase p's source
// planes landed; outstanding ds_reads at any barrier never alias the plane being staged.
// NOTE: all acc[][] indexing is compile-time (full unroll) — runtime indexing demotes
// the accumulator to scratch (prior session R4: 5x regression).
__global__ __launch_bounds__(512, 2) void gemm_kernel(const unsigned short* __restrict__ A,
                                                      const unsigned short* __restrict__ B,
                                                      float* __restrict__ out) {
    const int K = 2048;
    __shared__ alignas(16) unsigned short SM[65536];   // 128 KB

    const int tid = threadIdx.x;
    const int wid = tid >> 6, lane = tid & 63;
    const int lm = lane & 15, quad = lane >> 4;
    const int wm = wid >> 2, wn = wid & 3;     // 2 x 4 wave grid, per-wave C patch 128x64
    const int row0 = blockIdx.y * 256;         // A rows (M = o*8+ra*4+a)
    const int col0 = blockIdx.x * 256;         // B rows (N = n*4+c)

    // staging: plane = 1024 units of 16B; unit u: row=u>>2, chunk j=u&3, src j^=(row>>1)&3
    size_t gA[2], gB[2];
#pragma unroll
    for (int p = 0; p < 2; ++p) {
        int u = p * 512 + tid;
        int r = u >> 2, j = (u & 3) ^ ((r >> 1) & 3);
        gA[p] = (size_t)(row0 + r) * K + j * 8;
        gB[p] = (size_t)(col0 + r) * K + j * 8;
    }

    // frag read offsets (shorts, rel. to plane base), swizzled to match staging
    const int swz = (lm >> 1) & 3;
    const int aoff = (wm * 128 + lm) * 32 + (quad ^ swz) * 8;
    const int boff = (wn * 64 + lm) * 32 + (quad ^ swz) * 8;

    f32x4 acc[8][4];
#pragma unroll
    for (int i = 0; i < 8; ++i)
#pragma unroll
        for (int j = 0; j < 4; ++j) acc[i][j] = (f32x4){0.f, 0.f, 0.f, 0.f};

    // stage plane `slot` (0:A.ks0 1:B.ks0 2:A.ks1 3:B.ks1) of tile tt -> buf[tt&1]
    auto STAGE = [&](int tt, int slot) {
        const int ks = slot >> 1;
        const size_t ko = (size_t)tt * 64 + ks * 32;
        const int dst = (tt & 1) * 32768 + slot * 8192;
        const unsigned short* base = (slot & 1) ? B : A;
        const size_t g0 = (slot & 1) ? gB[0] : gA[0];
        const size_t g1 = (slot & 1) ? gB[1] : gA[1];
        __builtin_amdgcn_global_load_lds((const AS1 void*)(base + g0 + ko),
                                         (AS3 void*)&SM[dst + wid * 512], 16, 0, 0);
        __builtin_amdgcn_global_load_lds((const AS1 void*)(base + g1 + ko),
                                         (AS3 void*)&SM[dst + 4096 + wid * 512], 16, 0, 0);
    };

    // prologue: tile 0 fully staged (slots in order -> vmcnt math below)
    STAGE(0, 0); STAGE(0, 1); STAGE(0, 2); STAGE(0, 3);

    bf16x8 a0[4], a1[4], bv[4];
    for (int t = 0; t < 31; ++t) {
        const int bb = (t & 1) * 32768;
        // -- phase 0 (ks0, fm0-3): needs planes 0,1 of tile t (all but last 4 loads)
        asm volatile("s_waitcnt vmcnt(4)" ::: "memory");
        __builtin_amdgcn_s_barrier();
#pragma unroll
        for (int f = 0; f < 4; ++f) a0[f] = *(const bf16x8*)&SM[bb + aoff + f * 512];
#pragma unroll
        for (int f = 0; f < 4; ++f) bv[f] = *(const bf16x8*)&SM[bb + 8192 + boff + f * 512];
        STAGE(t + 1, 0);
        __builtin_amdgcn_s_barrier();
        __builtin_amdgcn_s_setprio(1);
#pragma unroll
        for (int f = 0; f < 4; ++f)
#pragma unroll
            for (int n = 0; n < 4; ++n)
                acc[f][n] = __builtin_amdgcn_mfma_f32_16x16x32_bf16(a0[f], bv[n], acc[f][n], 0, 0, 0);
        __builtin_amdgcn_s_setprio(0);
        // -- phase 1 (ks0, fm4-7)
#pragma unroll
        for (int f = 0; f < 4; ++f) a1[f] = *(const bf16x8*)&SM[bb + aoff + (f + 4) * 512];
        STAGE(t + 1, 1);
        __builtin_amdgcn_s_barrier();
        __builtin_amdgcn_s_setprio(1);
#pragma unroll
        for (int f = 0; f < 4; ++f)
#pragma unroll
            for (int n = 0; n < 4; ++n)
                acc[f + 4][n] = __builtin_amdgcn_mfma_f32_16x16x32_bf16(a1[f], bv[n], acc[f + 4][n], 0, 0, 0);
        __builtin_amdgcn_s_setprio(0);
        // -- phase 2 (ks1, fm0-3): needs planes 2,3 of tile t (all but last 4 loads)
        asm volatile("s_waitcnt vmcnt(4)" ::: "memory");
        __builtin_amdgcn_s_barrier();
#pragma unroll
        for (int f = 0; f < 4; ++f) a0[f] = *(const bf16x8*)&SM[bb + 16384 + aoff + f * 512];
#pragma unroll
        for (int f = 0; f < 4; ++f) bv[f] = *(const bf16x8*)&SM[bb + 24576 + boff + f * 512];
        STAGE(t + 1, 2);
        __builtin_amdgcn_s_barrier();
        __builtin_amdgcn_s_setprio(1);
#pragma unroll
        for (int f = 0; f < 4; ++f)
#pragma unroll
            for (int n = 0; n < 4; ++n)
                acc[f][n] = __builtin_amdgcn_mfma_f32_16x16x32_bf16(a0[f], bv[n], acc[f][n], 0, 0, 0);
        __builtin_amdgcn_s_setprio(0);
        // -- phase 3 (ks1, fm4-7)
#pragma unroll
        for (int f = 0; f < 4; ++f) a1[f] = *(const bf16x8*)&SM[bb + 16384 + aoff + (f + 4) * 512];
        STAGE(t + 1, 3);
        __builtin_amdgcn_s_barrier();
        __builtin_amdgcn_s_setprio(1);
#pragma unroll
        for (int f = 0; f < 4; ++f)
#pragma unroll
            for (int n = 0; n < 4; ++n)
                acc[f + 4][n] = __builtin_amdgcn_mfma_f32_16x16x32_bf16(a1[f], bv[n], acc[f + 4][n], 0, 0, 0);
        __builtin_amdgcn_s_setprio(0);
    }
    {   // peeled tile 31: no staging; final drain at phase 2
        const int bb = 32768;
        asm volatile("s_waitcnt vmcnt(4)" ::: "memory");
        __builtin_amdgcn_s_barrier();
#pragma unroll
        for (int f = 0; f < 4; ++f) a0[f] = *(const bf16x8*)&SM[bb + aoff + f * 512];
#pragma unroll
        for (int f = 0; f < 4; ++f) bv[f] = *(const bf16x8*)&SM[bb + 8192 + boff + f * 512];
        __builtin_amdgcn_s_barrier();
        __builtin_amdgcn_s_setprio(1);
#pragma unroll
        for (int f = 0; f < 4; ++f)
#pragma unroll
            for (int n = 0; n < 4; ++n)
                acc[f][n] = __builtin_amdgcn_mfma_f32_16x16x32_bf16(a0[f], bv[n], acc[f][n], 0, 0, 0);
        __builtin_amdgcn_s_setprio(0);
#pragma unroll
        for (int f = 0; f < 4; ++f) a1[f] = *(const bf16x8*)&SM[bb + aoff + (f + 4) * 512];
        __builtin_amdgcn_s_barrier();
        __builtin_amdgcn_s_setprio(1);
#pragma unroll
        for (int f = 0; f < 4; ++f)
#pragma unroll
            for (int n = 0; n < 4; ++n)
                acc[f + 4][n] = __builtin_amdgcn_mfma_f32_16x16x32_bf16(a1[f], bv[n], acc[f + 4][n], 0, 0, 0);
        __builtin_amdgcn_s_setprio(0);
        asm volatile("s_waitcnt vmcnt(0)" ::: "memory");
        __builtin_amdgcn_s_barrier();
#pragma unroll
        for (int f = 0; f < 4; ++f) a0[f] = *(const bf16x8*)&SM[bb + 16384 + aoff + f * 512];
#pragma unroll
        for (int f = 0; f < 4; ++f) bv[f] = *(const bf16x8*)&SM[bb + 24576 + boff + f * 512];
        __builtin_amdgcn_s_barrier();
        __builtin_amdgcn_s_setprio(1);
#pragma unroll
        for (int f = 0; f < 4; ++f)
#pragma unroll
            for (int n = 0; n < 4; ++n)
                acc[f][n] = __builtin_amdgcn_mfma_f32_16x16x32_bf16(a0[f], bv[n], acc[f][n], 0, 0, 0);
        __builtin_amdgcn_s_setprio(0);
#pragma unroll
        for (int f = 0; f < 4; ++f) a1[f] = *(const bf16x8*)&SM[bb + 16384 + aoff + (f + 4) * 512];
        __builtin_amdgcn_s_barrier();
        __builtin_amdgcn_s_setprio(1);
#pragma unroll
        for (int f = 0; f < 4; ++f)
#pragma unroll
            for (int n = 0; n < 4; ++n)
                acc[f + 4][n] = __builtin_amdgcn_mfma_f32_16x16x32_bf16(a1[f], bv[n], acc[f + 4][n], 0, 0, 0);
        __builtin_amdgcn_s_setprio(0);
    }
    __syncthreads();   // LDS reuse boundary: K-loop buffers -> per-wave epilogue scratch

    // ---- fused epilogue (unchanged, verified): per-wave 32x64 f32 stripes ----
    float* scrw = (float*)SM + wid * 2048;     // 8 KB per wave (64 KB total)
    const int nl = lane >> 2, ol = lane & 3;   // 4 consecutive o's in adjacent lanes
#pragma unroll
    for (int s = 0; s < 4; ++s) {              // fm pair {2s, 2s+1} = C rows [s*32, s*32+32)
#pragma unroll
        for (int h = 0; h < 2; ++h)
#pragma unroll
            for (int fn = 0; fn < 4; ++fn)
#pragma unroll
                for (int r = 0; r < 4; ++r) {
                    int rw = h * 16 + quad * 4 + r;
                    int cc = (fn * 16 + lm) ^ (quad << 3);   // (rw>>2)&3 == quad
                    scrw[rw * 64 + cc] = acc[s * 2 + h][fn][r];
                }
        asm volatile("s_waitcnt lgkmcnt(0)" ::: "memory");
        float V[32];   // V[ra*16 + a*4 + c]
#pragma unroll
        for (int u = 0; u < 8; ++u) {          // u = ra*4 + a
            int row = ol * 8 + u;
            int cb = (nl * 4) ^ (((row >> 2) & 3) << 3);
            float4 f = *(const float4*)&scrw[row * 64 + cb];
            int vi = (u >> 2) * 16 + (u & 3) * 4;
            V[vi + 0] = f.x; V[vi + 1] = f.y; V[vi + 2] = f.z; V[vi + 3] = f.w;
        }
        float xa[32];
        float ss = 0.f;
#pragma unroll
        for (int Ab = 0; Ab < 32; ++Ab) {
            float sv = 0.f;
#pragma unroll
            for (int a = 0; a < 4; ++a) {
                const int c = BL.m[Ab].col[a];
                const int p = BL.m[Ab].ph[a];
                float vv = V[(p & 1) * 16 + a * 4 + c];
                sv += (p & 2) ? -vv : vv;
            }
            sv *= 0.25f;
            xa[Ab] = sv;
            ss += sv * sv;
        }
        float inv = rsqrtf(ss + 1e-6f);
        int o = (row0 >> 3) + wm * 16 + s * 4 + ol;
        int n = (col0 >> 2) + wn * 16 + nl;
        float4* op = (float4*)(out + ((size_t)n * 256 + o) * 32);
#pragma unroll
        for (int q = 0; q < 8; ++q) {
            float4 f;
            f.x = xa[q * 4 + 0] * inv; f.y = xa[q * 4 + 1] * inv;
            f.z = xa[q * 4 + 2] * inv; f.w = xa[q * 4 + 3] * inv;
            op[q] = f;
        }
        asm volatile("s_waitcnt lgkmcnt(0)" ::: "memory");   // stripe reads done before rewrite
    }
}

extern "C" void kernel_launch(void* const* d_in, const int* in_sizes, int n_in,
                              void* d_out, int out_size, void* d_ws, size_t ws_size,
                              hipStream_t stream) {
    const float* x = (const float*)d_in[0];   // [4,512,256,32]
    const float* w = (const float*)d_in[1];   // [256,256,32]
    float* out = (float*)d_out;               // [4,512,256,32]

    unsigned short* Wr = (unsigned short*)d_ws;                             //  8,388,608 B
    unsigned short* Xb = (unsigned short*)((char*)d_ws + 8388608);          // 33,554,432 B

    hipLaunchKernelGGL(xform_kernel, dim3(2304),  dim3(256), 0, stream, x, w, Xb, Wr);
    hipLaunchKernelGGL(gemm_kernel,  dim3(32, 8), dim3(512), 0, stream, Wr, Xb, out);
}